// Round 1
// 1489.040 us; speedup vs baseline: 1.0214x; 1.0214x over previous
//
#include <hip/hip_runtime.h>

// Problem constants
#define BDIM 256   // batch
#define TDIM 256   // timesteps
#define IDIM 512   // input dim
#define HDIM 512   // hidden dim
#define G4   2048  // 4*H gate rows

#define HBW64 32768ull                 // ull words per h buffer (256*512/4)
#define SENT  0x7FC07FC07FC07FC0ull    // 4x bf16 NaN: unreachable by valid h

typedef __attribute__((ext_vector_type(4))) float f32x4;
typedef __attribute__((ext_vector_type(8))) short short8;     // 8 bf16 MFMA frag
typedef __attribute__((ext_vector_type(8))) unsigned short u16x8;
typedef __attribute__((ext_vector_type(4))) unsigned short u16x4;
typedef unsigned long long ull;

__device__ __forceinline__ unsigned short f2bf(float f) {
  union { float f; unsigned u; } v; v.f = f;
  unsigned r = v.u + 0x7FFFu + ((v.u >> 16) & 1u);   // RNE
  return (unsigned short)(r >> 16);
}
__device__ __forceinline__ float bf2f(unsigned short h) {
  union { unsigned u; float f; } v; v.u = ((unsigned)h) << 16; return v.f;
}
__device__ __forceinline__ float sigmoidf_fast(float x) {
  return 1.0f / (1.0f + __expf(-x));
}
__device__ __forceinline__ float tanhf_fast(float x) {
  float e = __expf(2.0f * x);
  return 1.0f - 2.0f / (e + 1.0f);
}
// async global->LDS 16B DMA (dst = wave-uniform base + lane*16)
__device__ __forceinline__ void gl_lds16(const unsigned short* g, unsigned short* l) {
  __builtin_amdgcn_global_load_lds(
      (const __attribute__((address_space(1))) unsigned int*)g,
      (__attribute__((address_space(3))) unsigned int*)l, 16, 0, 0);
}

// xg scatter offset shared by both GEMM epilogues.
// Layout: ((t*8 + bb)*8 + jw)*8192 + q*2048 + (b&31)*64 + jc
__device__ __forceinline__ size_t xg_off(int m, int n) {
  int b = m >> 8, t = m & 255;
  int q = n >> 9, jcol = n & 511;
  return (((size_t)t * 8 + (b >> 5)) * 8 + (jcol >> 6)) * 8192
         + (size_t)q * 2048 + (b & 31) * 64 + (jcol & 63);
}

// ---------------------------------------------------------------------------
// fp32 -> bf16 pre-convert of x (33.5M) and W_ih (1M). 8 elems/thread.
// ---------------------------------------------------------------------------
__global__ void __launch_bounds__(256) convert_bf16(
    const float* __restrict__ x, const float* __restrict__ w,
    unsigned short* __restrict__ xb, unsigned short* __restrict__ wb)
{
  const size_t NX8 = (size_t)BDIM * TDIM * IDIM / 8;   // 4194304
  const size_t NW8 = (size_t)G4 * IDIM / 8;            // 131072
  size_t idx = (size_t)blockIdx.x * 256 + threadIdx.x;
  const float4* sp; u16x8* dp; size_t i;
  if (idx < NX8)      { sp = (const float4*)x; dp = (u16x8*)xb; i = idx; }
  else if (idx < NX8 + NW8) { sp = (const float4*)w; dp = (u16x8*)wb; i = idx - NX8; }
  else return;
  float4 a = sp[i * 2], b = sp[i * 2 + 1];
  u16x8 o = { f2bf(a.x), f2bf(a.y), f2bf(a.z), f2bf(a.w),
              f2bf(b.x), f2bf(b.y), f2bf(b.z), f2bf(b.w) };
  dp[i] = o;
}

// ---------------------------------------------------------------------------
// Launch-time arming of the rotating h buffers:
//   buf0 <- sentinel (receives h_0, polled at t=1)
//   buf3 <- zeros    (h_{-1}, consumed un-polled... polled but never sentinel)
// buf1/buf2 are armed in-kernel (wipe at t=0 / t=1) before first polled (t=2/t=3).
// Plain stores are fine: kernel-boundary flush orders them vs the scan's
// agent-scope loads.
// ---------------------------------------------------------------------------
__global__ void __launch_bounds__(256) init_bufs(unsigned short* __restrict__ hb)
{
  size_t i = (size_t)blockIdx.x * 256 + threadIdx.x;   // 65536 total
  ull* b = (ull*)hb;
  if (i < HBW64)            b[i] = SENT;                       // buf0
  else if (i < 2 * HBW64)   b[3 * HBW64 + (i - HBW64)] = 0ull; // buf3
}

// ---------------------------------------------------------------------------
// Phase 1 (fast): m97-style bf16 GEMM, 128x128 tile, BK=32, global_load_lds 16B.
// ---------------------------------------------------------------------------
__global__ void __launch_bounds__(256, 2) xg_gemm_bf16(
    const unsigned short* __restrict__ Xb, const unsigned short* __restrict__ Wb,
    const float* __restrict__ b_ih, const float* __restrict__ b_hh,
    unsigned short* __restrict__ xg)
{
  __shared__ unsigned short sA[128 * 32];
  __shared__ unsigned short sB[128 * 32];

  const int tid  = threadIdx.x;
  const int lane = tid & 63;
  const int wave = tid >> 6;
  const int l15  = lane & 15;
  const int quad = lane >> 4;
  const int nt = blockIdx.x & 15;
  const int mt = blockIdx.x >> 4;
  const int wm = (wave >> 1) * 64;
  const int wn = (wave & 1) * 64;

  f32x4 acc[4][4];
  #pragma unroll
  for (int i = 0; i < 4; ++i)
    #pragma unroll
    for (int j = 0; j < 4; ++j)
      acc[i][j] = (f32x4){0.f, 0.f, 0.f, 0.f};

  for (int kt = 0; kt < 16; ++kt) {
    #pragma unroll
    for (int i = 0; i < 2; ++i) {
      int c   = wave * 128 + i * 64 + lane;
      int row = c >> 2, cg = c & 3;
      const unsigned short* ga = Xb + (size_t)(mt * 128 + row) * 512 + kt * 32 + cg * 8;
      gl_lds16(ga, sA + (size_t)(wave * 128 + i * 64) * 8);
      const unsigned short* gb = Wb + (size_t)(nt * 128 + row) * 512 + kt * 32 + cg * 8;
      gl_lds16(gb, sB + (size_t)(wave * 128 + i * 64) * 8);
    }
    __syncthreads();

    short8 af[4], bfr[4];
    #pragma unroll
    for (int i = 0; i < 4; ++i) {
      af[i]  = *(const short8*)&sA[(wm + i * 16 + l15) * 32 + quad * 8];
      bfr[i] = *(const short8*)&sB[(wn + i * 16 + l15) * 32 + quad * 8];
    }
    #pragma unroll
    for (int am = 0; am < 4; ++am)
      #pragma unroll
      for (int an = 0; an < 4; ++an)
        acc[am][an] = __builtin_amdgcn_mfma_f32_16x16x32_bf16(
            af[am], bfr[an], acc[am][an], 0, 0, 0);
    __syncthreads();
  }

  float biasv[4];
  #pragma unroll
  for (int an = 0; an < 4; ++an) {
    int n = nt * 128 + wn + an * 16 + l15;
    biasv[an] = b_ih[n] + b_hh[n];
  }
  #pragma unroll
  for (int am = 0; am < 4; ++am)
    #pragma unroll
    for (int reg = 0; reg < 4; ++reg) {
      int m = mt * 128 + wm + am * 16 + quad * 4 + reg;
      #pragma unroll
      for (int an = 0; an < 4; ++an) {
        int n = nt * 128 + wn + an * 16 + l15;
        xg[xg_off(m, n)] = f2bf(acc[am][an][reg] + biasv[an]);
      }
    }
}

// ---------------------------------------------------------------------------
// Phase 1 (fallback, ws too small): fp32-staging GEMM.
// ---------------------------------------------------------------------------
__global__ void __launch_bounds__(256, 2) xg_gemm_f32(
    const float* __restrict__ X, const float* __restrict__ Wih,
    const float* __restrict__ b_ih, const float* __restrict__ b_hh,
    unsigned short* __restrict__ xg)
{
  __shared__ unsigned short sA[128][40];
  __shared__ unsigned short sB[128][40];

  const int tid  = threadIdx.x;
  const int lane = tid & 63;
  const int wave = tid >> 6;
  const int l15  = lane & 15;
  const int quad = lane >> 4;
  const int nt = blockIdx.x;
  const int mt = blockIdx.y;
  const int wm = (wave >> 1) * 64;
  const int wn = (wave & 1) * 64;
  const int r    = tid >> 1;
  const int half = (tid & 1) * 16;

  const float* arow = X   + (size_t)(mt * 128 + r) * 512 + half;
  const float* brow = Wih + (size_t)(nt * 128 + r) * 512 + half;

  f32x4 acc[4][4];
  #pragma unroll
  for (int i = 0; i < 4; ++i)
    #pragma unroll
    for (int j = 0; j < 4; ++j)
      acc[i][j] = (f32x4){0.f, 0.f, 0.f, 0.f};

  for (int kt = 0; kt < 16; ++kt) {
    const float* ap = arow + kt * 32;
    const float* bp = brow + kt * 32;
    #pragma unroll
    for (int i = 0; i < 4; ++i) {
      float4 a = ((const float4*)ap)[i];
      u16x4 av = { f2bf(a.x), f2bf(a.y), f2bf(a.z), f2bf(a.w) };
      *(u16x4*)&sA[r][half + i * 4] = av;
      float4 b = ((const float4*)bp)[i];
      u16x4 bv = { f2bf(b.x), f2bf(b.y), f2bf(b.z), f2bf(b.w) };
      *(u16x4*)&sB[r][half + i * 4] = bv;
    }
    __syncthreads();
    short8 af[4], bfr[4];
    #pragma unroll
    for (int i = 0; i < 4; ++i) {
      af[i]  = *(const short8*)&sA[wm + i * 16 + l15][quad * 8];
      bfr[i] = *(const short8*)&sB[wn + i * 16 + l15][quad * 8];
    }
    #pragma unroll
    for (int am = 0; am < 4; ++am)
      #pragma unroll
      for (int an = 0; an < 4; ++an)
        acc[am][an] = __builtin_amdgcn_mfma_f32_16x16x32_bf16(
            af[am], bfr[an], acc[am][an], 0, 0, 0);
    __syncthreads();
  }

  float biasv[4];
  #pragma unroll
  for (int an = 0; an < 4; ++an) {
    int n = nt * 128 + wn + an * 16 + l15;
    biasv[an] = b_ih[n] + b_hh[n];
  }
  #pragma unroll
  for (int am = 0; am < 4; ++am)
    #pragma unroll
    for (int reg = 0; reg < 4; ++reg) {
      int m = mt * 128 + wm + am * 16 + quad * 4 + reg;
      #pragma unroll
      for (int an = 0; an < 4; ++an) {
        int n = nt * 128 + wn + an * 16 + l15;
        xg[xg_off(m, n)] = f2bf(acc[am][an][reg] + biasv[an]);
      }
    }
}

// ---------------------------------------------------------------------------
// Phase 2: persistent scan — R7: sentinel-tagged data polling (no flags).
//
// Protocol (replaces R3-R6 flag sync; cuts the per-step serial chain from
// ~4 MALL round trips to ~2):
//  * h_t lives in buf[t&3] of 4 rotating 256KB buffers. Each 8B word holds
//    4 bf16 h-values; 8B atomic stores are single-copy atomic, so a word is
//    either the full sentinel (4x bf16 NaN = 0x7FC0, unreachable by any
//    finite h = sigmoid*tanh) or fully valid h_t data. Consumers poll the
//    DATA words directly: staging load == readiness detection. No flag hop,
//    no producer-side vmcnt drain before a flag, no barrier (d).
//  * Re-arm: at step t each thread sentinel-stores the exact word it will
//    write at t+1 (same address, same thread -> per-location coherence
//    orders wipe before next data store). "s_waitcnt vmcnt(0)" before the
//    h_t store orders wipe-ack before h_t is observable; a consumer polls
//    buf[(t+1)&3] only after consuming h_t, hence after the wipe committed
//    -> stale h_{t-3} can never be accepted. Safe to wipe at the top of
//    step t: all peers finished reading buf[(t+1)&3] (as h_{t-3}, at their
//    step t-2) before publishing h_{t-2}, which we consumed at step t-1.
//  * Init: buf0=sentinel + buf3=zeros(h_{-1}) via init_bufs; buf1/buf2 are
//    armed by the t=0/t=1 wipes before their first poll at t=2/t=3.
//  * Bounded spin (guard) degrades to NaN output (absmax fail), never hangs.
// Barriers per step: 2 (post-stage, post-sG) vs 4 before.
// ---------------------------------------------------------------------------
__global__ void __launch_bounds__(512, 2) lstm_scan(
    const float* __restrict__ Whh, const unsigned short* __restrict__ xg,
    unsigned short* __restrict__ hb)
{
  __shared__ unsigned short sH[32][520];   // h slice, +8 pad
  __shared__ float sG[32][260];            // gates, +4 pad

  const int tid  = threadIdx.x;
  const int lane = tid & 63;
  const int wave = tid >> 6;        // 0..7
  const int l15  = lane & 15;
  const int quad = lane >> 4;
  const int q    = wave >> 1;       // gate (i,f,g,o)
  const int np   = (wave & 1) * 2;  // n-subtile pair
  const int bb = blockIdx.x >> 3;   // batch block 0..7
  const int jw = blockIdx.x & 7;    // col block 0..7
  const int bbase = bb * 32;
  const int jbase = jw * 64;

  // One-time: W_hh -> 2x16 register B-frags per lane (128 VGPRs).
  short8 bfrag[2][16];
  #pragma unroll
  for (int n2 = 0; n2 < 2; ++n2) {
    const float* wrow = Whh + (size_t)(q * 512 + jbase + (np + n2) * 16 + l15) * 512;
    #pragma unroll
    for (int ks = 0; ks < 16; ++ks) {
      const float* p = wrow + ks * 32 + quad * 8;
      float4 f0 = ((const float4*)p)[0];
      float4 f1 = ((const float4*)p)[1];
      short8 v;
      v[0] = (short)f2bf(f0.x); v[1] = (short)f2bf(f0.y);
      v[2] = (short)f2bf(f0.z); v[3] = (short)f2bf(f0.w);
      v[4] = (short)f2bf(f1.x); v[5] = (short)f2bf(f1.y);
      v[6] = (short)f2bf(f1.z); v[7] = (short)f2bf(f1.w);
      bfrag[n2][ks] = v;
    }
  }

  const int r  = tid >> 4;          // gate-math row 0..31
  const int j0 = (tid & 15) * 4;    // gate-math col group
  float c[4] = {0.f, 0.f, 0.f, 0.f};

  ull* hb64 = (ull*)hb;
  // The one 8B h-word this thread owns (writes every step, wipes one step ahead).
  const size_t myw = (size_t)(bbase + r) * 128 + (size_t)((jbase + j0) >> 2);

  for (int t = 0; t < TDIM; ++t) {
    const ull* srcb = hb64 + (size_t)((t + 3) & 3) * HBW64;   // h_{t-1}
    ull*       dstb = hb64 + (size_t)(t & 3) * HBW64;         // h_t

    // Re-arm own t+1 word early: ack arrives long before the vmcnt(0) below.
    // Skip once no future step will poll it (last poll of buf[(t+1)&3] is t+2).
    if (t < TDIM - 2) {
      ull* wipb = hb64 + (size_t)((t + 1) & 3) * HBW64;
      __hip_atomic_store(wipb + myw, SENT, __ATOMIC_RELAXED,
                         __HIP_MEMORY_SCOPE_AGENT);
    }

    // xg loads for step t (plain cached; in flight across poll-stage).
    const unsigned short* xgb = xg + (((size_t)t * 8 + bb) * 8 + jw) * 8192;
    ull xv64[4];
    #pragma unroll
    for (int qq = 0; qq < 4; ++qq)
      xv64[qq] = *(const ull*)(xgb + qq * 2048 + r * 64 + j0);

    // Poll-stage h_{t-1}: issue all 8 words, then spin re-loading only the
    // words still holding the sentinel. All 512 threads poll in parallel;
    // distinct addresses -> no single-line ping-pong like the old flag word.
    const ull* src = srcb + (size_t)bbase * 128;
    ull hv[8];
    #pragma unroll
    for (int i = 0; i < 8; ++i)
      hv[i] = __hip_atomic_load(src + i * 512 + tid, __ATOMIC_RELAXED,
                                __HIP_MEMORY_SCOPE_AGENT);
    for (int guard = 0; guard < (1 << 18); ++guard) {
      int bad = 0;
      #pragma unroll
      for (int i = 0; i < 8; ++i) bad |= (int)(hv[i] == SENT) << i;
      if (!bad) break;
      __builtin_amdgcn_s_sleep(1);
      #pragma unroll
      for (int i = 0; i < 8; ++i)
        if (bad & (1 << i))
          hv[i] = __hip_atomic_load(src + i * 512 + tid, __ATOMIC_RELAXED,
                                    __HIP_MEMORY_SCOPE_AGENT);
    }
    #pragma unroll
    for (int i = 0; i < 8; ++i) {
      int idx = i * 512 + tid;
      *(ull*)&sH[idx >> 7][(idx & 127) * 4] = hv[i];
    }
    __syncthreads();   // (b) sH staged

    // G-tile MFMA: 2 m-subtiles x 2 n-subtiles, K=512.
    f32x4 acc[2][2];
    acc[0][0] = acc[0][1] = acc[1][0] = acc[1][1] = (f32x4){0.f,0.f,0.f,0.f};
    #pragma unroll
    for (int ks = 0; ks < 16; ++ks) {
      int koff = ks * 32 + quad * 8;
      short8 a0 = *(const short8*)&sH[l15][koff];
      short8 a1 = *(const short8*)&sH[16 + l15][koff];
      acc[0][0] = __builtin_amdgcn_mfma_f32_16x16x32_bf16(a0, bfrag[0][ks], acc[0][0], 0, 0, 0);
      acc[1][0] = __builtin_amdgcn_mfma_f32_16x16x32_bf16(a1, bfrag[0][ks], acc[1][0], 0, 0, 0);
      acc[0][1] = __builtin_amdgcn_mfma_f32_16x16x32_bf16(a0, bfrag[1][ks], acc[0][1], 0, 0, 0);
      acc[1][1] = __builtin_amdgcn_mfma_f32_16x16x32_bf16(a1, bfrag[1][ks], acc[1][1], 0, 0, 0);
    }
    #pragma unroll
    for (int m = 0; m < 2; ++m)
      #pragma unroll
      for (int n2 = 0; n2 < 2; ++n2) {
        int col = q * 64 + (np + n2) * 16 + l15;
        #pragma unroll
        for (int rr = 0; rr < 4; ++rr)
          sG[m * 16 + quad * 4 + rr][col] = acc[m][n2][rr];
      }
    __syncthreads();   // (c) sG ready; also fences sH reads vs next staging

    // Gate math: 4 cells (r, j0..j0+3).
    {
      float4 GI = *(const float4*)&sG[r][j0];
      float4 GF = *(const float4*)&sG[r][64 + j0];
      float4 GG = *(const float4*)&sG[r][128 + j0];
      float4 GO = *(const float4*)&sG[r][192 + j0];
      u16x4 xi  = __builtin_bit_cast(u16x4, xv64[0]);
      u16x4 xf  = __builtin_bit_cast(u16x4, xv64[1]);
      u16x4 xgv = __builtin_bit_cast(u16x4, xv64[2]);
      u16x4 xo  = __builtin_bit_cast(u16x4, xv64[3]);
      float gi[4] = {GI.x, GI.y, GI.z, GI.w};
      float gf[4] = {GF.x, GF.y, GF.z, GF.w};
      float gg[4] = {GG.x, GG.y, GG.z, GG.w};
      float go[4] = {GO.x, GO.y, GO.z, GO.w};
      float h4[4];
      #pragma unroll
      for (int k = 0; k < 4; ++k) {
        float vi = sigmoidf_fast(gi[k] + bf2f(xi[k]));
        float vf = sigmoidf_fast(gf[k] + bf2f(xf[k]));
        float vg = tanhf_fast   (gg[k] + bf2f(xgv[k]));
        float vo = sigmoidf_fast(go[k] + bf2f(xo[k]));
        c[k] = vf * c[k] + vi * vg;
        h4[k] = vo * tanhf_fast(c[k]);
      }
      ull hvout = (ull)f2bf(h4[0])
                | ((ull)f2bf(h4[1]) << 16)
                | ((ull)f2bf(h4[2]) << 32)
                | ((ull)f2bf(h4[3]) << 48);
      // Order: this step's wipe (issued at top, ack long since arrived) must
      // be committed before h_t becomes observable. vmcnt(0) is ~free here —
      // all loads already returned; only the wipe ack could be outstanding.
      asm volatile("s_waitcnt vmcnt(0)" ::: "memory");
      __hip_atomic_store(dstb + myw, hvout, __ATOMIC_RELAXED,
                         __HIP_MEMORY_SCOPE_AGENT);
    }
    // No barrier (d), no flag. Next iteration's sH writes are fenced by (c);
    // its sG writes are fenced by the next (b).
  }
}

// ---------------------------------------------------------------------------
// Head: out[b] = h_last[b,:] . fc_w + fc_b
// ---------------------------------------------------------------------------
__global__ void head_kernel(const unsigned short* __restrict__ h,
                            const float* __restrict__ fc_w,
                            const float* __restrict__ fc_b,
                            float* __restrict__ out)
{
  const int b = blockIdx.x;
  const int lane = threadIdx.x;
  const unsigned short* hr = h + (size_t)b * 512;
  float s = 0.f;
  #pragma unroll
  for (int i = 0; i < 8; ++i) {
    int idx = lane + i * 64;
    s += bf2f(hr[idx]) * fc_w[idx];
  }
  #pragma unroll
  for (int off = 32; off > 0; off >>= 1) s += __shfl_down(s, off);
  if (lane == 0) out[b] = s + fc_b[0];
}

// ---------------------------------------------------------------------------
extern "C" void kernel_launch(void* const* d_in, const int* in_sizes, int n_in,
                              void* d_out, int out_size, void* d_ws, size_t ws_size,
                              hipStream_t stream) {
  const float* x    = (const float*)d_in[0];
  const float* W_ih = (const float*)d_in[1];
  const float* W_hh = (const float*)d_in[2];
  const float* b_ih = (const float*)d_in[3];
  const float* b_hh = (const float*)d_in[4];
  const float* fc_w = (const float*)d_in[5];
  const float* fc_b = (const float*)d_in[6];
  float* out = (float*)d_out;

  // Workspace layout:
  //   [0, 268435456)        xg bf16 (scan-blocked)
  //   [XG, XG+64MB)         xb bf16 (fast GEMM input; DEAD after xg_gemm_bf16)
  //   [XG+64MB, XG+66MB)    wb bf16
  //   hb (4 x 256KB rotating h buffers) ALIASES the first 1MB of xb —
  //   init_bufs runs AFTER the GEMM, so the alias is safe and the total
  //   footprint does not grow vs R6.
  const size_t XG  = (size_t)BDIM * TDIM * G4 * 2;     // 268435456
  char* ws = (char*)d_ws;
  unsigned short* xg = (unsigned short*)ws;
  unsigned short* hb = (unsigned short*)(ws + XG);     // 4*HBW64*8 = 1MB
  const size_t XB_OFF = XG;
  const size_t WB_OFF = XG + (size_t)BDIM * TDIM * IDIM * 2;  // +64MB
  const size_t NEED   = WB_OFF + (size_t)G4 * IDIM * 2;       // +2MB

  if (ws_size >= NEED) {
    unsigned short* xb = (unsigned short*)(ws + XB_OFF);
    unsigned short* wb = (unsigned short*)(ws + WB_OFF);
    convert_bf16<<<16896, 256, 0, stream>>>(x, W_ih, xb, wb);
    xg_gemm_bf16<<<8192, 256, 0, stream>>>(xb, wb, b_ih, b_hh, xg);
  } else {
    xg_gemm_f32<<<dim3(16, 512), 256, 0, stream>>>(x, W_ih, b_ih, b_hh, xg);
  }
  // Arm buf0 (sentinel) + zero buf3 (h_{-1}). MUST come after the GEMM: hb
  // aliases xb. Kernel-boundary ordering makes it visible to lstm_scan.
  init_bufs<<<256, 256, 0, stream>>>(hb);
  lstm_scan<<<64, 512, 0, stream>>>(W_hh, xg, hb);
  // h_255 lives in buf[255 & 3] = buf3.
  head_kernel<<<BDIM, 64, 0, stream>>>(hb + 3 * (size_t)HBW64 * 4, fc_w, fc_b, out);
}

// Round 4
// 1486.128 us; speedup vs baseline: 1.0234x; 1.0020x over previous
//
#include <hip/hip_runtime.h>

// Problem constants
#define BDIM 256   // batch
#define TDIM 256   // timesteps
#define IDIM 512   // input dim
#define HDIM 512   // hidden dim
#define G4   2048  // 4*H gate rows

#define HBW64 32768ull                 // ull words per h buffer (256*512/4)
#define SENT  0x7FC07FC07FC07FC0ull    // 4x bf16 NaN: unreachable by valid h

typedef __attribute__((ext_vector_type(4))) float f32x4;
typedef __attribute__((ext_vector_type(8))) short short8;     // 8 bf16 MFMA frag
typedef __attribute__((ext_vector_type(8))) unsigned short u16x8;
typedef __attribute__((ext_vector_type(4))) unsigned short u16x4;
typedef unsigned long long ull;

__device__ __forceinline__ unsigned short f2bf(float f) {
  union { float f; unsigned u; } v; v.f = f;
  unsigned r = v.u + 0x7FFFu + ((v.u >> 16) & 1u);   // RNE
  return (unsigned short)(r >> 16);
}
__device__ __forceinline__ float bf2f(unsigned short h) {
  union { unsigned u; float f; } v; v.u = ((unsigned)h) << 16; return v.f;
}
__device__ __forceinline__ float sigmoidf_fast(float x) {
  return 1.0f / (1.0f + __expf(-x));
}
__device__ __forceinline__ float tanhf_fast(float x) {
  float e = __expf(2.0f * x);
  return 1.0f - 2.0f / (e + 1.0f);
}
// async global->LDS 16B DMA (dst = wave-uniform base + lane*16)
__device__ __forceinline__ void gl_lds16(const unsigned short* g, unsigned short* l) {
  __builtin_amdgcn_global_load_lds(
      (const __attribute__((address_space(1))) unsigned int*)g,
      (__attribute__((address_space(3))) unsigned int*)l, 16, 0, 0);
}

// xg scatter offset shared by both GEMM epilogues.
// Layout: ((t*8 + bb)*8 + jw)*8192 + q*2048 + (b&31)*64 + jc
__device__ __forceinline__ size_t xg_off(int m, int n) {
  int b = m >> 8, t = m & 255;
  int q = n >> 9, jcol = n & 511;
  return (((size_t)t * 8 + (b >> 5)) * 8 + (jcol >> 6)) * 8192
         + (size_t)q * 2048 + (b & 31) * 64 + (jcol & 63);
}

// ---------------------------------------------------------------------------
// fp32 -> bf16 pre-convert of x (33.5M) and W_ih (1M). 8 elems/thread.
// ---------------------------------------------------------------------------
__global__ void __launch_bounds__(256) convert_bf16(
    const float* __restrict__ x, const float* __restrict__ w,
    unsigned short* __restrict__ xb, unsigned short* __restrict__ wb)
{
  const size_t NX8 = (size_t)BDIM * TDIM * IDIM / 8;   // 4194304
  const size_t NW8 = (size_t)G4 * IDIM / 8;            // 131072
  size_t idx = (size_t)blockIdx.x * 256 + threadIdx.x;
  const float4* sp; u16x8* dp; size_t i;
  if (idx < NX8)      { sp = (const float4*)x; dp = (u16x8*)xb; i = idx; }
  else if (idx < NX8 + NW8) { sp = (const float4*)w; dp = (u16x8*)wb; i = idx - NX8; }
  else return;
  float4 a = sp[i * 2], b = sp[i * 2 + 1];
  u16x8 o = { f2bf(a.x), f2bf(a.y), f2bf(a.z), f2bf(a.w),
              f2bf(b.x), f2bf(b.y), f2bf(b.z), f2bf(b.w) };
  dp[i] = o;
}

// ---------------------------------------------------------------------------
// Arm the rotating h buffers:
//   buf0 <- sentinel (receives h_0, polled at t=1)
//   buf3 <- zeros    (h_{-1})
// buf1/buf2 are armed in-kernel (wipe at t=0 / t=1) before first polled.
// ---------------------------------------------------------------------------
__global__ void __launch_bounds__(256) init_bufs(unsigned short* __restrict__ hb)
{
  size_t i = (size_t)blockIdx.x * 256 + threadIdx.x;   // 65536 total
  ull* b = (ull*)hb;
  if (i < HBW64)            b[i] = SENT;                       // buf0
  else if (i < 2 * HBW64)   b[3 * HBW64 + (i - HBW64)] = 0ull; // buf3
}

// ---------------------------------------------------------------------------
// Phase 1 (fast): m97-style bf16 GEMM, 128x128 tile, BK=32, global_load_lds 16B.
// xg stores are NON-TEMPORAL (nt): 512MB stream must not evict the MALL.
// ---------------------------------------------------------------------------
__global__ void __launch_bounds__(256, 2) xg_gemm_bf16(
    const unsigned short* __restrict__ Xb, const unsigned short* __restrict__ Wb,
    const float* __restrict__ b_ih, const float* __restrict__ b_hh,
    unsigned short* __restrict__ xg)
{
  __shared__ unsigned short sA[128 * 32];
  __shared__ unsigned short sB[128 * 32];

  const int tid  = threadIdx.x;
  const int lane = tid & 63;
  const int wave = tid >> 6;
  const int l15  = lane & 15;
  const int quad = lane >> 4;
  const int nt = blockIdx.x & 15;
  const int mt = blockIdx.x >> 4;
  const int wm = (wave >> 1) * 64;
  const int wn = (wave & 1) * 64;

  f32x4 acc[4][4];
  #pragma unroll
  for (int i = 0; i < 4; ++i)
    #pragma unroll
    for (int j = 0; j < 4; ++j)
      acc[i][j] = (f32x4){0.f, 0.f, 0.f, 0.f};

  for (int kt = 0; kt < 16; ++kt) {
    #pragma unroll
    for (int i = 0; i < 2; ++i) {
      int c   = wave * 128 + i * 64 + lane;
      int row = c >> 2, cg = c & 3;
      const unsigned short* ga = Xb + (size_t)(mt * 128 + row) * 512 + kt * 32 + cg * 8;
      gl_lds16(ga, sA + (size_t)(wave * 128 + i * 64) * 8);
      const unsigned short* gb = Wb + (size_t)(nt * 128 + row) * 512 + kt * 32 + cg * 8;
      gl_lds16(gb, sB + (size_t)(wave * 128 + i * 64) * 8);
    }
    __syncthreads();

    short8 af[4], bfr[4];
    #pragma unroll
    for (int i = 0; i < 4; ++i) {
      af[i]  = *(const short8*)&sA[(wm + i * 16 + l15) * 32 + quad * 8];
      bfr[i] = *(const short8*)&sB[(wn + i * 16 + l15) * 32 + quad * 8];
    }
    #pragma unroll
    for (int am = 0; am < 4; ++am)
      #pragma unroll
      for (int an = 0; an < 4; ++an)
        acc[am][an] = __builtin_amdgcn_mfma_f32_16x16x32_bf16(
            af[am], bfr[an], acc[am][an], 0, 0, 0);
    __syncthreads();
  }

  float biasv[4];
  #pragma unroll
  for (int an = 0; an < 4; ++an) {
    int n = nt * 128 + wn + an * 16 + l15;
    biasv[an] = b_ih[n] + b_hh[n];
  }
  #pragma unroll
  for (int am = 0; am < 4; ++am)
    #pragma unroll
    for (int reg = 0; reg < 4; ++reg) {
      int m = mt * 128 + wm + am * 16 + quad * 4 + reg;
      #pragma unroll
      for (int an = 0; an < 4; ++an) {
        int n = nt * 128 + wn + an * 16 + l15;
        __builtin_nontemporal_store(f2bf(acc[am][an][reg] + biasv[an]),
                                    &xg[xg_off(m, n)]);
      }
    }
}

// ---------------------------------------------------------------------------
// Phase 1 (fallback, ws too small): fp32-staging GEMM. nt xg stores likewise.
// ---------------------------------------------------------------------------
__global__ void __launch_bounds__(256, 2) xg_gemm_f32(
    const float* __restrict__ X, const float* __restrict__ Wih,
    const float* __restrict__ b_ih, const float* __restrict__ b_hh,
    unsigned short* __restrict__ xg)
{
  __shared__ unsigned short sA[128][40];
  __shared__ unsigned short sB[128][40];

  const int tid  = threadIdx.x;
  const int lane = tid & 63;
  const int wave = tid >> 6;
  const int l15  = lane & 15;
  const int quad = lane >> 4;
  const int nt = blockIdx.x;
  const int mt = blockIdx.y;
  const int wm = (wave >> 1) * 64;
  const int wn = (wave & 1) * 64;
  const int r    = tid >> 1;
  const int half = (tid & 1) * 16;

  const float* arow = X   + (size_t)(mt * 128 + r) * 512 + half;
  const float* brow = Wih + (size_t)(nt * 128 + r) * 512 + half;

  f32x4 acc[4][4];
  #pragma unroll
  for (int i = 0; i < 4; ++i)
    #pragma unroll
    for (int j = 0; j < 4; ++j)
      acc[i][j] = (f32x4){0.f, 0.f, 0.f, 0.f};

  for (int kt = 0; kt < 16; ++kt) {
    const float* ap = arow + kt * 32;
    const float* bp = brow + kt * 32;
    #pragma unroll
    for (int i = 0; i < 4; ++i) {
      float4 a = ((const float4*)ap)[i];
      u16x4 av = { f2bf(a.x), f2bf(a.y), f2bf(a.z), f2bf(a.w) };
      *(u16x4*)&sA[r][half + i * 4] = av;
      float4 b = ((const float4*)bp)[i];
      u16x4 bv = { f2bf(b.x), f2bf(b.y), f2bf(b.z), f2bf(b.w) };
      *(u16x4*)&sB[r][half + i * 4] = bv;
    }
    __syncthreads();
    short8 af[4], bfr[4];
    #pragma unroll
    for (int i = 0; i < 4; ++i) {
      af[i]  = *(const short8*)&sA[wm + i * 16 + l15][quad * 8];
      bfr[i] = *(const short8*)&sB[wn + i * 16 + l15][quad * 8];
    }
    #pragma unroll
    for (int am = 0; am < 4; ++am)
      #pragma unroll
      for (int an = 0; an < 4; ++an)
        acc[am][an] = __builtin_amdgcn_mfma_f32_16x16x32_bf16(
            af[am], bfr[an], acc[am][an], 0, 0, 0);
    __syncthreads();
  }

  float biasv[4];
  #pragma unroll
  for (int an = 0; an < 4; ++an) {
    int n = nt * 128 + wn + an * 16 + l15;
    biasv[an] = b_ih[n] + b_hh[n];
  }
  #pragma unroll
  for (int am = 0; am < 4; ++am)
    #pragma unroll
    for (int reg = 0; reg < 4; ++reg) {
      int m = mt * 128 + wm + am * 16 + quad * 4 + reg;
      #pragma unroll
      for (int an = 0; an < 4; ++an) {
        int n = nt * 128 + wn + an * 16 + l15;
        __builtin_nontemporal_store(f2bf(acc[am][an][reg] + biasv[an]),
                                    &xg[xg_off(m, n)]);
      }
    }
}

// ---------------------------------------------------------------------------
// Phase 2: persistent scan — R10 = R7 (proven, 1489us) + NON-TEMPORAL xg loads.
//
// Theory: R0/R1 FETCH_SIZE (400-468MB) exceeds the 256MB xg consumption ->
// the 2MB/step xg stream evicts the ~1.25MB h/flag hot set from the MALL,
// so every h-exchange hop runs at HBM-miss latency (~900+cy). nt loads keep
// xg out of the caches; the h hot set stays MALL-resident and the sentinel
// protocol's round trips shorten to MALL-hit latency.
//
// Protocol (unchanged from R7, two passing runs):
//  * h_t in buf[t&3] of 4 rotating 256KB buffers; 8B words are either the
//    full sentinel (4x bf16 NaN, unreachable by valid h) or full valid data
//    (8B stores are single-copy atomic). Consumers poll the data words.
//  * Re-arm: at step t each thread sentinel-wipes its own t+1 word;
//    vmcnt(0) before the h_t store orders wipe-commit < h_t-visible;
//    transitivity prevents stale h_{t-3} acceptance.
//  * Init: buf0=sentinel, buf3=zeros (h_{-1}); buf1/buf2 armed at t=0/t=1.
//  * Guard-bounded spins -> worst case NaN (visible), never a hang.
// ---------------------------------------------------------------------------
__global__ void __launch_bounds__(512, 2) lstm_scan(
    const float* __restrict__ Whh, const unsigned short* __restrict__ xg,
    unsigned short* __restrict__ hb)
{
  __shared__ unsigned short sH[32][520];   // h slice, +8 pad
  __shared__ float sG[32][260];            // gates, +4 pad

  const int tid  = threadIdx.x;
  const int lane = tid & 63;
  const int wave = tid >> 6;        // 0..7
  const int l15  = lane & 15;
  const int quad = lane >> 4;
  const int q    = wave >> 1;       // gate (i,f,g,o)
  const int np   = (wave & 1) * 2;  // n-subtile pair
  const int bb = blockIdx.x >> 3;   // batch block 0..7
  const int jw = blockIdx.x & 7;    // col block 0..7
  const int bbase = bb * 32;
  const int jbase = jw * 64;

  // One-time: W_hh -> 2x16 register B-frags per lane (128 VGPRs).
  short8 bfrag[2][16];
  #pragma unroll
  for (int n2 = 0; n2 < 2; ++n2) {
    const float* wrow = Whh + (size_t)(q * 512 + jbase + (np + n2) * 16 + l15) * 512;
    #pragma unroll
    for (int ks = 0; ks < 16; ++ks) {
      const float* p = wrow + ks * 32 + quad * 8;
      float4 f0 = ((const float4*)p)[0];
      float4 f1 = ((const float4*)p)[1];
      short8 v;
      v[0] = (short)f2bf(f0.x); v[1] = (short)f2bf(f0.y);
      v[2] = (short)f2bf(f0.z); v[3] = (short)f2bf(f0.w);
      v[4] = (short)f2bf(f1.x); v[5] = (short)f2bf(f1.y);
      v[6] = (short)f2bf(f1.z); v[7] = (short)f2bf(f1.w);
      bfrag[n2][ks] = v;
    }
  }

  const int r  = tid >> 4;          // gate-math row 0..31
  const int j0 = (tid & 15) * 4;    // gate-math col group
  float c[4] = {0.f, 0.f, 0.f, 0.f};

  ull* hb64 = (ull*)hb;
  // The one 8B h-word this thread owns (writes every step, wipes one ahead).
  const size_t myw = (size_t)(bbase + r) * 128 + (size_t)((jbase + j0) >> 2);

  for (int t = 0; t < TDIM; ++t) {
    const ull* srcb = hb64 + (size_t)((t + 3) & 3) * HBW64;   // h_{t-1}
    ull*       dstb = hb64 + (size_t)(t & 3) * HBW64;         // h_t

    // Re-arm own t+1 word early: ack arrives long before the vmcnt(0) below.
    if (t < TDIM - 2) {
      ull* wipb = hb64 + (size_t)((t + 1) & 3) * HBW64;
      __hip_atomic_store(wipb + myw, SENT, __ATOMIC_RELAXED,
                         __HIP_MEMORY_SCOPE_AGENT);
    }

    // xg loads for step t — NON-TEMPORAL: stream must not evict the MALL
    // hot set. Issued at the top so HBM latency overlaps poll + MFMA.
    const unsigned short* xgb = xg + (((size_t)t * 8 + bb) * 8 + jw) * 8192;
    ull xv64[4];
    #pragma unroll
    for (int qq = 0; qq < 4; ++qq)
      xv64[qq] = __builtin_nontemporal_load(
          (const ull*)(xgb + qq * 2048 + r * 64 + j0));

    // Poll-stage h_{t-1}: issue all 8 words, spin only on sentinel words.
    const ull* src = srcb + (size_t)bbase * 128;
    ull hv[8];
    #pragma unroll
    for (int i = 0; i < 8; ++i)
      hv[i] = __hip_atomic_load(src + i * 512 + tid, __ATOMIC_RELAXED,
                                __HIP_MEMORY_SCOPE_AGENT);
    for (int guard = 0; guard < (1 << 18); ++guard) {
      int bad = 0;
      #pragma unroll
      for (int i = 0; i < 8; ++i) bad |= (int)(hv[i] == SENT) << i;
      if (!bad) break;
      __builtin_amdgcn_s_sleep(1);
      #pragma unroll
      for (int i = 0; i < 8; ++i)
        if (bad & (1 << i))
          hv[i] = __hip_atomic_load(src + i * 512 + tid, __ATOMIC_RELAXED,
                                    __HIP_MEMORY_SCOPE_AGENT);
    }
    #pragma unroll
    for (int i = 0; i < 8; ++i) {
      int idx = i * 512 + tid;
      *(ull*)&sH[idx >> 7][(idx & 127) * 4] = hv[i];
    }
    __syncthreads();   // (b) sH staged

    // G-tile MFMA: 2 m-subtiles x 2 n-subtiles, K=512.
    f32x4 acc[2][2];
    acc[0][0] = acc[0][1] = acc[1][0] = acc[1][1] = (f32x4){0.f,0.f,0.f,0.f};
    #pragma unroll
    for (int ks = 0; ks < 16; ++ks) {
      int koff = ks * 32 + quad * 8;
      short8 a0 = *(const short8*)&sH[l15][koff];
      short8 a1 = *(const short8*)&sH[16 + l15][koff];
      acc[0][0] = __builtin_amdgcn_mfma_f32_16x16x32_bf16(a0, bfrag[0][ks], acc[0][0], 0, 0, 0);
      acc[1][0] = __builtin_amdgcn_mfma_f32_16x16x32_bf16(a1, bfrag[0][ks], acc[1][0], 0, 0, 0);
      acc[0][1] = __builtin_amdgcn_mfma_f32_16x16x32_bf16(a0, bfrag[1][ks], acc[0][1], 0, 0, 0);
      acc[1][1] = __builtin_amdgcn_mfma_f32_16x16x32_bf16(a1, bfrag[1][ks], acc[1][1], 0, 0, 0);
    }
    #pragma unroll
    for (int m = 0; m < 2; ++m)
      #pragma unroll
      for (int n2 = 0; n2 < 2; ++n2) {
        int col = q * 64 + (np + n2) * 16 + l15;
        #pragma unroll
        for (int rr = 0; rr < 4; ++rr)
          sG[m * 16 + quad * 4 + rr][col] = acc[m][n2][rr];
      }
    __syncthreads();   // (c) sG ready; also fences sH reads vs next staging

    // Gate math: 4 cells (r, j0..j0+3).
    {
      float4 GI = *(const float4*)&sG[r][j0];
      float4 GF = *(const float4*)&sG[r][64 + j0];
      float4 GG = *(const float4*)&sG[r][128 + j0];
      float4 GO = *(const float4*)&sG[r][192 + j0];
      u16x4 xi  = __builtin_bit_cast(u16x4, xv64[0]);
      u16x4 xf  = __builtin_bit_cast(u16x4, xv64[1]);
      u16x4 xgv = __builtin_bit_cast(u16x4, xv64[2]);
      u16x4 xo  = __builtin_bit_cast(u16x4, xv64[3]);
      float gi[4] = {GI.x, GI.y, GI.z, GI.w};
      float gf[4] = {GF.x, GF.y, GF.z, GF.w};
      float gg[4] = {GG.x, GG.y, GG.z, GG.w};
      float go[4] = {GO.x, GO.y, GO.z, GO.w};
      float h4[4];
      #pragma unroll
      for (int k = 0; k < 4; ++k) {
        float vi = sigmoidf_fast(gi[k] + bf2f(xi[k]));
        float vf = sigmoidf_fast(gf[k] + bf2f(xf[k]));
        float vg = tanhf_fast   (gg[k] + bf2f(xgv[k]));
        float vo = sigmoidf_fast(go[k] + bf2f(xo[k]));
        c[k] = vf * c[k] + vi * vg;
        h4[k] = vo * tanhf_fast(c[k]);
      }
      ull hvout = (ull)f2bf(h4[0])
                | ((ull)f2bf(h4[1]) << 16)
                | ((ull)f2bf(h4[2]) << 32)
                | ((ull)f2bf(h4[3]) << 48);
      // Order: this step's wipe must be committed before h_t is observable.
      asm volatile("s_waitcnt vmcnt(0)" ::: "memory");
      __hip_atomic_store(dstb + myw, hvout, __ATOMIC_RELAXED,
                         __HIP_MEMORY_SCOPE_AGENT);
    }
    // No barrier (d), no flag. Next iteration's sH writes are fenced by (c);
    // its sG writes are fenced by the next (b).
  }
}

// ---------------------------------------------------------------------------
// Head: out[b] = h_last[b,:] . fc_w + fc_b
// ---------------------------------------------------------------------------
__global__ void head_kernel(const unsigned short* __restrict__ h,
                            const float* __restrict__ fc_w,
                            const float* __restrict__ fc_b,
                            float* __restrict__ out)
{
  const int b = blockIdx.x;
  const int lane = threadIdx.x;
  const unsigned short* hr = h + (size_t)b * 512;
  float s = 0.f;
  #pragma unroll
  for (int i = 0; i < 8; ++i) {
    int idx = lane + i * 64;
    s += bf2f(hr[idx]) * fc_w[idx];
  }
  #pragma unroll
  for (int off = 32; off > 0; off >>= 1) s += __shfl_down(s, off);
  if (lane == 0) out[b] = s + fc_b[0];
}

// ---------------------------------------------------------------------------
extern "C" void kernel_launch(void* const* d_in, const int* in_sizes, int n_in,
                              void* d_out, int out_size, void* d_ws, size_t ws_size,
                              hipStream_t stream) {
  const float* x    = (const float*)d_in[0];
  const float* W_ih = (const float*)d_in[1];
  const float* W_hh = (const float*)d_in[2];
  const float* b_ih = (const float*)d_in[3];
  const float* b_hh = (const float*)d_in[4];
  const float* fc_w = (const float*)d_in[5];
  const float* fc_b = (const float*)d_in[6];
  float* out = (float*)d_out;

  // Workspace layout:
  //   [0, XG)                xg bf16 (scan-blocked)
  //   [XG, XG+64MB)          xb bf16 (fast GEMM input; DEAD after xg_gemm_bf16)
  //   [XG+64MB, XG+66MB)     wb bf16
  //   hb (4 x 256KB rotating h buffers) ALIASES the first 1MB of xb —
  //   init_bufs runs AFTER the GEMM, so the alias is safe.
  const size_t XG  = (size_t)BDIM * TDIM * G4 * 2;     // 268435456
  char* ws = (char*)d_ws;
  unsigned short* xg = (unsigned short*)ws;
  unsigned short* hb = (unsigned short*)(ws + XG);     // 4*HBW64*8 = 1MB
  const size_t XB_OFF = XG;
  const size_t WB_OFF = XG + (size_t)BDIM * TDIM * IDIM * 2;  // +64MB
  const size_t NEED   = WB_OFF + (size_t)G4 * IDIM * 2;       // +2MB

  if (ws_size >= NEED) {
    unsigned short* xb = (unsigned short*)(ws + XB_OFF);
    unsigned short* wb = (unsigned short*)(ws + WB_OFF);
    convert_bf16<<<16896, 256, 0, stream>>>(x, W_ih, xb, wb);
    xg_gemm_bf16<<<8192, 256, 0, stream>>>(xb, wb, b_ih, b_hh, xg);
  } else {
    xg_gemm_f32<<<dim3(16, 512), 256, 0, stream>>>(x, W_ih, b_ih, b_hh, xg);
  }
  // Arm buf0 (sentinel) + zero buf3 (h_{-1}). MUST come after the GEMM: hb
  // aliases xb. Kernel-boundary ordering makes it visible to lstm_scan.
  init_bufs<<<256, 256, 0, stream>>>(hb);
  lstm_scan<<<64, 512, 0, stream>>>(W_hh, xg, hb);
  // T=256: final write (t=255) went to buf[255&3] = buf3.
  head_kernel<<<BDIM, 64, 0, stream>>>(hb + 3 * (size_t)HBW64 * 4, fc_w, fc_b, out);
}